// Round 3
// baseline (1531.842 us; speedup 1.0000x reference)
//
#include <hip/hip_runtime.h>
#include <stdint.h>

#define NNODES 50000
#define NEDGES 1000000
#define FD 256
#define NCD 300
#define NCP 304   // padded leading dim for the 300-wide intermediate
#define EDIM 64

typedef unsigned short u16;
typedef __attribute__((ext_vector_type(8))) short short8;   // 8 x bf16 bits (MFMA A/B frag)
typedef __attribute__((ext_vector_type(4))) float floatx4;

__device__ __forceinline__ float bf2f(u16 x) {
    union { unsigned u; float f; } c; c.u = ((unsigned)x) << 16; return c.f;
}
__device__ __forceinline__ u16 f2bf(float f) {
    union { float f; unsigned u; } c; c.f = f;
    unsigned u = c.u;
    return (u16)((u + 0x7fffu + ((u >> 16) & 1u)) >> 16);   // round-to-nearest-even
}

// ---------- runtime input-dtype probe ----------
// bf16 N(0,1) data: exponent field of every u16 <= 129 (|x| < 8).
// f32 data read as u16: low halves are uniform mantissa bits -> exp field ~255 fast.
__global__ void detect_kernel(const u16* p, int* flag) {
    __shared__ int smax;
    if (threadIdx.x == 0) smax = 0;
    __syncthreads();
    int m = 0;
    for (int i = threadIdx.x; i < 8192; i += 256) {
        int e = (p[i] >> 7) & 0xFF;
        m = m > e ? m : e;
    }
    atomicMax(&smax, m);
    __syncthreads();
    if (threadIdx.x == 0) *flag = (smax >= 140) ? 1 : 0;
}

// ---------- weights/biases -> bf16 arena (1,682,304 B) ----------
// prefix offsets (elements, all 8-aligned); b_p1 padded 300->304
__global__ void convert_kernel(u16* arena, const int* flagp,
    const void* wexp, const void* bexp, const void* wp1, const void* bp1,
    const void* wp2, const void* bp2, const void* wconv, const void* bconv,
    const void* wo1, const void* bo1, const void* wo2, const void* bo2)
{
    const long offs[13] = {0,16384,16640,106640,106944,183744,184000,
                           577216,577984,709056,709568,840640,841152};
    const int reals[12] = {16384,256,90000,300,76800,256,393216,768,
                           131072,512,131072,512};
    long gid = (long)blockIdx.x * 256 + threadIdx.x;
    if (gid >= 841152) return;
    const void* srcs[12] = {wexp,bexp,wp1,bp1,wp2,bp2,wconv,bconv,wo1,bo1,wo2,bo2};
    int fl = *flagp;
    int t = 0;
    #pragma unroll
    for (int i = 1; i < 12; ++i) if (gid >= offs[i]) t = i;
    long local = gid - offs[t];
    u16 v = 0;
    if (local < reals[t])
        v = fl ? f2bf(((const float*)srcs[t])[local]) : ((const u16*)srcs[t])[local];
    arena[gid] = v;
}

// ---------------- CSR build ----------------
__global__ void count_kernel(const int* dst, int* deg) {
    int e = blockIdx.x * blockDim.x + threadIdx.x;
    if (e < NEDGES) atomicAdd(&deg[dst[e]], 1);
}

__global__ __launch_bounds__(1024) void scan_kernel(const int* deg,
        int* row_start, int* cursor, float* inv_w) {
    __shared__ int part[1024];
    int t = threadIdx.x;
    const int CH = (NNODES + 1023) / 1024;  // 49
    int base = t * CH;
    int s = 0;
    for (int i = 0; i < CH; ++i) { int idx = base + i; if (idx < NNODES) s += deg[idx]; }
    part[t] = s;
    __syncthreads();
    for (int off = 1; off < 1024; off <<= 1) {
        int v = (t >= off) ? part[t - off] : 0;
        __syncthreads();
        part[t] += v;
        __syncthreads();
    }
    int run = part[t] - s;
    for (int i = 0; i < CH; ++i) {
        int idx = base + i;
        if (idx < NNODES) {
            int d = deg[idx];
            row_start[idx] = run;
            cursor[idx] = run;
            inv_w[idx] = 1.0f / (float)(d > 0 ? d : 1);
            run += d;
        }
    }
    if (t == 0) row_start[NNODES] = NEDGES;
}

__global__ void fill_kernel(const int* src, const int* dst, int* cursor, int* esrc) {
    int e = blockIdx.x * blockDim.x + threadIdx.x;
    if (e < NEDGES) {
        int v = dst[e];
        int pos = atomicAdd(&cursor[v], 1);
        if ((unsigned)pos < (unsigned)NEDGES) esrc[pos] = src[e];
    }
}

// ---------------- bf16 MFMA GEMM: out = act(A[:,0:K] @ W^T + b) (+addsrc) ------
// A dtype: bf16, or f32 converted on load when (dflag && *dflag). A2 (concat at
// col KA) always bf16. out bf16, or f32 via outf. In-place A==out safe (own-rows).
template<int NT>
__global__ __launch_bounds__(256) void gemm_kernel(
    const void* A, const void* A2, int KA, int lda, const int* dflag,
    const u16* W, int ldw, const u16* bias,
    u16* out, float* outf, int ldo,
    const u16* addsrc,
    int M, int N, int K, int act)
{
    __shared__ __align__(16) u16 sA[64][40];
    __shared__ __align__(16) u16 sB[NT * 16][40];
    const int t = threadIdx.x;
    const int wave = t >> 6, lane = t & 63;
    const int quad = lane >> 4, l16 = lane & 15;
    const int bm = blockIdx.y * 64, bn = blockIdx.x * (NT * 16);
    const bool af32 = (dflag != nullptr) && (*dflag != 0);

    floatx4 acc[NT];
    #pragma unroll
    for (int i = 0; i < NT; ++i) acc[i] = (floatx4){0.f, 0.f, 0.f, 0.f};

    for (int kt = 0; kt < K; kt += 32) {
        // stage A tile 64x32 (virtual concat [A | A2] at column KA)
        #pragma unroll
        for (int it = 0; it < 2; ++it) {
            int i4 = t + it * 256;
            int row = i4 >> 3;
            int c4 = (i4 & 7) << 2;
            int gm = bm + row;
            int gk = kt + c4;
            ushort4 tv;
            bool inA2 = (A2 != nullptr) && (gk >= KA);
            if (gm < M && gk + 4 <= K) {
                if (inA2) {
                    tv = *(const ushort4*)((const u16*)A2 + (size_t)gm * lda + (gk - KA));
                } else if (af32) {
                    float4 fv = *(const float4*)((const float*)A + (size_t)gm * lda + gk);
                    tv.x = f2bf(fv.x); tv.y = f2bf(fv.y); tv.z = f2bf(fv.z); tv.w = f2bf(fv.w);
                } else {
                    tv = *(const ushort4*)((const u16*)A + (size_t)gm * lda + gk);
                }
            } else {
                u16 tmp[4];
                for (int j = 0; j < 4; ++j) {
                    int gkj = gk + j; u16 x = 0;
                    if (gm < M && gkj < K) {
                        if (A2 != nullptr && gkj >= KA)
                            x = ((const u16*)A2)[(size_t)gm * lda + (gkj - KA)];
                        else if (af32)
                            x = f2bf(((const float*)A)[(size_t)gm * lda + gkj]);
                        else
                            x = ((const u16*)A)[(size_t)gm * lda + gkj];
                    }
                    tmp[j] = x;
                }
                tv.x = tmp[0]; tv.y = tmp[1]; tv.z = tmp[2]; tv.w = tmp[3];
            }
            *(ushort4*)&sA[row][c4] = tv;
        }
        // stage W tile (NT*16)x32 (bf16 arena)
        #pragma unroll
        for (int it = 0; it < NT / 2; ++it) {
            int i4 = t + it * 256;
            int row = i4 >> 3;
            int c4 = (i4 & 7) << 2;
            int gn = bn + row;
            int gk = kt + c4;
            ushort4 tv;
            if (gn < N && gk + 4 <= K) {
                tv = *(const ushort4*)(W + (size_t)gn * ldw + gk);
            } else {
                u16 tmp[4];
                for (int j = 0; j < 4; ++j)
                    tmp[j] = (gn < N && gk + j < K) ? W[(size_t)gn * ldw + gk + j] : (u16)0;
                tv.x = tmp[0]; tv.y = tmp[1]; tv.z = tmp[2]; tv.w = tmp[3];
            }
            *(ushort4*)&sB[row][c4] = tv;
        }
        __syncthreads();
        // A-frag: m = lane&15, k = quad*8+j (HW-verified layout)
        short8 af = *(const short8*)&sA[wave * 16 + l16][quad * 8];
        #pragma unroll
        for (int nt = 0; nt < NT; ++nt) {
            short8 bf = *(const short8*)&sB[nt * 16 + l16][quad * 8];
            acc[nt] = __builtin_amdgcn_mfma_f32_16x16x32_bf16(af, bf, acc[nt], 0, 0, 0);
        }
        __syncthreads();
    }

    // epilogue: C/D layout col = lane&15, row = quad*4 + reg (m89/m91 verified)
    #pragma unroll
    for (int nt = 0; nt < NT; ++nt) {
        int gn = bn + nt * 16 + l16;
        if (gn >= N) continue;
        float bv = (bias != nullptr) ? bf2f(bias[gn]) : 0.0f;
        #pragma unroll
        for (int r = 0; r < 4; ++r) {
            int gm = bm + wave * 16 + quad * 4 + r;
            if (gm < M) {
                float v = acc[nt][r] + bv;
                if (act) v = v > 0.0f ? v : 0.1f * v;
                if (addsrc != nullptr) v += bf2f(addsrc[(size_t)gm * ldo + gn]);
                if (outf != nullptr) outf[(size_t)gm * ldo + gn] = v;
                else out[(size_t)gm * ldo + gn] = f2bf(v);
            }
        }
    }
}

// ---------------- neighbor-mean aggregation (pull, CSR) ----------------
__global__ __launch_bounds__(256) void agg_kernel(
    const u16* h, const int* row_start, const int* esrc,
    const float* inv_w, u16* out)
{
    int gid = blockIdx.x * blockDim.x + threadIdx.x;
    int wid = gid >> 6;
    int lane = gid & 63;
    if (wid >= NNODES) return;
    int e0 = row_start[wid], e1 = row_start[wid + 1];
    e0 = max(0, min(e0, NEDGES));
    e1 = max(e0, min(e1, NEDGES));
    float a0 = 0.f, a1 = 0.f, a2 = 0.f, a3 = 0.f;
    for (int e = e0; e < e1; ++e) {
        int u = esrc[e];
        if ((unsigned)u >= (unsigned)NNODES) u = 0;
        ushort4 tv = *(const ushort4*)(h + (size_t)u * FD + lane * 4);
        a0 += bf2f(tv.x); a1 += bf2f(tv.y); a2 += bf2f(tv.z); a3 += bf2f(tv.w);
    }
    float s = inv_w[wid];
    ushort4 ov;
    ov.x = f2bf(a0 * s); ov.y = f2bf(a1 * s); ov.z = f2bf(a2 * s); ov.w = f2bf(a3 * s);
    *(ushort4*)(out + (size_t)wid * FD + lane * 4) = ov;
}

// ------------- bf16 row lrelu + L2 normalize (in-place safe) -------------
__global__ __launch_bounds__(256) void norm_kernel(const u16* in, u16* out, int act)
{
    int gid = blockIdx.x * blockDim.x + threadIdx.x;
    int wid = gid >> 6, lane = gid & 63;
    if (wid >= NNODES) return;
    ushort4 tv = *(const ushort4*)(in + (size_t)wid * FD + lane * 4);
    u16 raw[4] = {tv.x, tv.y, tv.z, tv.w};
    float f[4]; float ss = 0.f;
    #pragma unroll
    for (int j = 0; j < 4; ++j) {
        float x = bf2f(raw[j]);
        if (act) x = x > 0.f ? x : 0.1f * x;
        f[j] = x; ss += x * x;
    }
    #pragma unroll
    for (int off = 32; off > 0; off >>= 1) ss += __shfl_xor(ss, off);
    float s = 1.0f / fmaxf(sqrtf(ss), 1e-6f);
    ushort4 ov;
    ov.x = f2bf(f[0] * s); ov.y = f2bf(f[1] * s);
    ov.z = f2bf(f[2] * s); ov.w = f2bf(f[3] * s);
    *(ushort4*)(out + (size_t)wid * FD + lane * 4) = ov;
}

// ------------- f32 final L2 normalize, in place on d_out -------------
__global__ __launch_bounds__(256) void normf_kernel(float* io)
{
    int gid = blockIdx.x * blockDim.x + threadIdx.x;
    int wid = gid >> 6, lane = gid & 63;
    if (wid >= NNODES) return;
    float4 v = *(float4*)(io + (size_t)wid * FD + lane * 4);
    float ss = v.x * v.x + v.y * v.y + v.z * v.z + v.w * v.w;
    #pragma unroll
    for (int off = 32; off > 0; off >>= 1) ss += __shfl_xor(ss, off);
    float s = 1.0f / fmaxf(sqrtf(ss), 1e-6f);
    v.x *= s; v.y *= s; v.z *= s; v.w *= s;
    *(float4*)(io + (size_t)wid * FD + lane * 4) = v;
}

extern "C" void kernel_launch(void* const* d_in, const int* in_sizes, int n_in,
                              void* d_out, int out_size, void* d_ws, size_t ws_size,
                              hipStream_t stream) {
    const void* content = d_in[1];
    const int* src      = (const int*)d_in[2];
    const int* dst      = (const int*)d_in[3];
    const void* emb     = d_in[4];

    // ---- workspace layout (~57.7 MB) ----
    char* ws = (char*)d_ws;
    u16* arena = (u16*)(ws);                       // 1,682,304 B weights/biases bf16
    u16* hbuf  = (u16*)(ws + 1682432);             // 25.6 MB
    u16* buf2  = (u16*)(ws + 27282432);            // 25.6 MB (h_agg / Wo1-out)
    u16* cbuf  = (u16*)(ws + 27282432);            // 30.4 MB init-only c, overlaps CSR (sequenced)
    int*   deg    = (int*)(ws + 52882432);
    int*   rs     = (int*)(ws + 53082624);
    int*   cursor = (int*)(ws + 53282816);
    float* inv_w  = (float*)(ws + 53483008);
    int*   esrc   = (int*)(ws + 53683200);         // 4 MB, ends 57,683,200
    int*   flag   = (int*)(ws + 57683200);

    // arena offsets (elements)
    u16* aWexp  = arena;            u16* aBexp  = arena + 16384;
    u16* aWp1   = arena + 16640;    u16* aBp1   = arena + 106640;
    u16* aWp2   = arena + 106944;   u16* aBp2   = arena + 183744;
    u16* aWconv = arena + 184000;   u16* aBconv = arena + 577216;
    u16* aWo1   = arena + 577984;   u16* aBo1   = arena + 709056;
    u16* aWo2   = arena + 709568;   u16* aBo2   = arena + 840640;

    const int MB = (NNODES + 63) / 64;  // 782
    dim3 blk(256);

    // ---- dtype probe + weight conversion (every call; ws re-poisoned) ----
    detect_kernel<<<1, 256, 0, stream>>>((const u16*)content, flag);
    convert_kernel<<<(841152 + 255) / 256, 256, 0, stream>>>(arena, flag,
        d_in[5], d_in[6], d_in[7], d_in[8], d_in[9], d_in[10], d_in[11],
        d_in[12], d_in[13], d_in[14], d_in[15], d_in[16]);

    // ---- init GEMMs (before CSR build: cbuf overlaps CSR region) ----
    // h = lrelu(emb @ W_exp^T + b_exp)
    gemm_kernel<4><<<dim3(FD / 64, MB), blk, 0, stream>>>(emb, nullptr, 0, EDIM, flag,
        aWexp, EDIM, aBexp, hbuf, nullptr, FD, nullptr, NNODES, FD, EDIM, 1);
    // c = lrelu(content @ W_p1^T + b_p1)
    gemm_kernel<4><<<dim3((NCD + 63) / 64, MB), blk, 0, stream>>>(content, nullptr, 0, NCD, flag,
        aWp1, NCD, aBp1, cbuf, nullptr, NCP, nullptr, NNODES, NCD, NCD, 1);
    // h = lrelu(c @ W_p2^T + b_p2) + h  (out aliases addsrc: same-thread read-then-write)
    gemm_kernel<4><<<dim3(FD / 64, MB), blk, 0, stream>>>(cbuf, nullptr, 0, NCP, nullptr,
        aWp2, NCD, aBp2, hbuf, nullptr, FD, hbuf, NNODES, FD, NCD, 1);

    // ---- CSR by destination (cbuf is dead now) ----
    hipMemsetAsync(deg, 0, (size_t)NNODES * 4, stream);
    count_kernel<<<(NEDGES + 255) / 256, 256, 0, stream>>>(dst, deg);
    scan_kernel<<<1, 1024, 0, stream>>>(deg, rs, cursor, inv_w);
    fill_kernel<<<(NEDGES + 255) / 256, 256, 0, stream>>>(src, dst, cursor, esrc);

    // ---- layers ----
    for (int i = 0; i < 3; ++i) {
        agg_kernel<<<(NNODES * 64) / 256, blk, 0, stream>>>(hbuf, rs, esrc, inv_w, buf2);
        if (i < 2) {
            // h_new = [h | h_agg] @ W_conv[i]^T + b_conv[i]  (K=512), in place into hbuf
            gemm_kernel<16><<<dim3(1, MB), blk, 0, stream>>>(hbuf, buf2, FD, FD, nullptr,
                aWconv + (size_t)i * FD * 2 * FD, 2 * FD, aBconv + (size_t)i * FD,
                hbuf, nullptr, FD, nullptr, NNODES, FD, 2 * FD, 0);
            norm_kernel<<<(NNODES * 64) / 256, blk, 0, stream>>>(hbuf, hbuf, 1);
            // h = lrelu(h_new @ Wo1^T + bo1) @ Wo2^T + bo2
            gemm_kernel<4><<<dim3(FD / 64, MB), blk, 0, stream>>>(hbuf, nullptr, 0, FD, nullptr,
                aWo1 + (size_t)i * FD * FD, FD, aBo1 + (size_t)i * FD, buf2, nullptr, FD,
                nullptr, NNODES, FD, FD, 1);
            gemm_kernel<4><<<dim3(FD / 64, MB), blk, 0, stream>>>(buf2, nullptr, 0, FD, nullptr,
                aWo2 + (size_t)i * FD * FD, FD, aBo2 + (size_t)i * FD, hbuf, nullptr, FD,
                nullptr, NNODES, FD, FD, 0);
        } else {
            // final conv in f32 straight into d_out, then f32 normalize in place
            gemm_kernel<16><<<dim3(1, MB), blk, 0, stream>>>(hbuf, buf2, FD, FD, nullptr,
                aWconv + (size_t)i * FD * 2 * FD, 2 * FD, aBconv + (size_t)i * FD,
                nullptr, (float*)d_out, FD, nullptr, NNODES, FD, 2 * FD, 0);
            normf_kernel<<<(NNODES * 64) / 256, blk, 0, stream>>>((float*)d_out);
        }
    }
}

// Round 4
// 1058.995 us; speedup vs baseline: 1.4465x; 1.4465x over previous
//
#include <hip/hip_runtime.h>
#include <stdint.h>

#define NNODES 50000
#define NEDGES 1000000
#define FD 256
#define NCD 300
#define NCP 304   // padded leading dim for the 300-wide intermediate
#define EDIM 64
#define NSCAN ((NNODES + 255) / 256)   // 196 scan blocks

typedef unsigned short u16;
typedef __attribute__((ext_vector_type(8))) short short8;   // 8 x bf16 bits (MFMA A/B frag)
typedef __attribute__((ext_vector_type(4))) float floatx4;

__device__ __forceinline__ float bf2f(u16 x) {
    union { unsigned u; float f; } c; c.u = ((unsigned)x) << 16; return c.f;
}
__device__ __forceinline__ u16 f2bf(float f) {
    union { float f; unsigned u; } c; c.f = f;
    unsigned u = c.u;
    return (u16)((u + 0x7fffu + ((u >> 16) & 1u)) >> 16);   // round-to-nearest-even
}
// async global->LDS, 16B per lane; LDS dest = wave-uniform base + lane*16 (m97 pattern)
__device__ __forceinline__ void gload16(const u16* g, u16* l) {
    __builtin_amdgcn_global_load_lds(
        (const __attribute__((address_space(1))) void*)g,
        (__attribute__((address_space(3))) void*)l, 16, 0, 0);
}

// ---------- runtime input-dtype probe (f32 vs bf16 harness feed) ----------
__global__ void detect_kernel(const u16* p, int* flag) {
    __shared__ int smax;
    if (threadIdx.x == 0) smax = 0;
    __syncthreads();
    int m = 0;
    for (int i = threadIdx.x; i < 8192; i += 256) {
        int e = (p[i] >> 7) & 0xFF;
        m = m > e ? m : e;
    }
    atomicMax(&smax, m);
    __syncthreads();
    if (threadIdx.x == 0) *flag = (smax >= 140) ? 1 : 0;
}

// ---------- weights/biases -> bf16 arena ----------
__global__ void convert_kernel(u16* arena, const int* flagp,
    const void* wexp, const void* bexp, const void* wp1, const void* bp1,
    const void* wp2, const void* bp2, const void* wconv, const void* bconv,
    const void* wo1, const void* bo1, const void* wo2, const void* bo2)
{
    const long offs[13] = {0,16384,16640,106640,106944,183744,184000,
                           577216,577984,709056,709568,840640,841152};
    const int reals[12] = {16384,256,90000,300,76800,256,393216,768,
                           131072,512,131072,512};
    long gid = (long)blockIdx.x * 256 + threadIdx.x;
    if (gid >= 841152) return;
    const void* srcs[12] = {wexp,bexp,wp1,bp1,wp2,bp2,wconv,bconv,wo1,bo1,wo2,bo2};
    int fl = *flagp;
    int t = 0;
    #pragma unroll
    for (int i = 1; i < 12; ++i) if (gid >= offs[i]) t = i;
    long local = gid - offs[t];
    u16 v = 0;
    if (local < reals[t])
        v = fl ? f2bf(((const float*)srcs[t])[local]) : ((const u16*)srcs[t])[local];
    arena[gid] = v;
}

// ---------------- CSR build ----------------
__global__ void count_kernel(const int* dst, int* deg) {
    int e = blockIdx.x * blockDim.x + threadIdx.x;
    if (e < NEDGES) atomicAdd(&deg[dst[e]], 1);
}

// multi-block scan: (1) per-block sums
__global__ __launch_bounds__(256) void scan1_kernel(const int* deg, int* bsum) {
    __shared__ int s[256];
    int t = threadIdx.x;
    int i = blockIdx.x * 256 + t;
    s[t] = (i < NNODES) ? deg[i] : 0;
    __syncthreads();
    #pragma unroll
    for (int off = 128; off > 0; off >>= 1) {
        if (t < off) s[t] += s[t + off];
        __syncthreads();
    }
    if (t == 0) bsum[blockIdx.x] = s[0];
}

// (2) single-block exclusive scan of NSCAN block sums (NSCAN <= 256)
__global__ __launch_bounds__(256) void scan2_kernel(int* bsum, int* row_start) {
    __shared__ int s[256];
    int t = threadIdx.x;
    int v = (t < NSCAN) ? bsum[t] : 0;
    s[t] = v;
    __syncthreads();
    for (int off = 1; off < 256; off <<= 1) {
        int x = (t >= off) ? s[t - off] : 0;
        __syncthreads();
        s[t] += x;
        __syncthreads();
    }
    if (t < NSCAN) bsum[t] = s[t] - v;   // exclusive
    if (t == 0) row_start[NNODES] = NEDGES;
}

// (3) per-block local exclusive scan + write row_start/cursor/inv_w
__global__ __launch_bounds__(256) void scan3_kernel(const int* deg, const int* bsum,
        int* row_start, int* cursor, float* inv_w) {
    __shared__ int s[256];
    int t = threadIdx.x;
    int i = blockIdx.x * 256 + t;
    int v = (i < NNODES) ? deg[i] : 0;
    s[t] = v;
    __syncthreads();
    for (int off = 1; off < 256; off <<= 1) {
        int x = (t >= off) ? s[t - off] : 0;
        __syncthreads();
        s[t] += x;
        __syncthreads();
    }
    if (i < NNODES) {
        int base = bsum[blockIdx.x] + s[t] - v;
        row_start[i] = base;
        cursor[i] = base;
        inv_w[i] = 1.0f / (float)(v > 0 ? v : 1);
    }
}

__global__ void fill_kernel(const int* src, const int* dst, int* cursor, int* esrc) {
    int e = blockIdx.x * blockDim.x + threadIdx.x;
    if (e < NEDGES) {
        int v = dst[e];
        int pos = atomicAdd(&cursor[v], 1);
        if ((unsigned)pos < (unsigned)NEDGES) esrc[pos] = src[e];
    }
}

// -------- fast 128x128 MFMA GEMM (m97 structure): out = act(A @ W^T + b) ------
// Requires: N multiple of 128, K multiple of 32, KA multiple of 32 (concat at KA).
// A row-overreads (bm+row up to bm+127 >= M) must stay inside the ws allocation;
// garbage rows never stored (MFMA C row m depends only on A row m).
__global__ __launch_bounds__(256) void gemm128_kernel(
    const u16* A, const u16* A2, int KA, int lda,
    const u16* W, int ldw, const u16* bias,
    u16* out, float* outf, int ldo,
    int M, int N, int K, int act)
{
    __shared__ __align__(16) u16 sA[128 * 32];   // [row][k] pitch 32 (no pad: gload16 layout)
    __shared__ __align__(16) u16 sB[128 * 32];
    const int t = threadIdx.x;
    const int wave = t >> 6, lane = t & 63;
    const int quad = lane >> 4, l16 = lane & 15;
    const int wm = wave >> 1, wn = wave & 1;
    const int bm = blockIdx.y * 128, bn = blockIdx.x * 128;
    const int lrow = lane >> 2;          // 0..15
    const int lcol = (lane & 3) * 8;     // 0,8,16,24

    floatx4 acc[4][4];
    #pragma unroll
    for (int i = 0; i < 4; ++i)
        #pragma unroll
        for (int j = 0; j < 4; ++j) acc[i][j] = (floatx4){0.f, 0.f, 0.f, 0.f};

    for (int kt = 0; kt < K; kt += 32) {
        const u16* Ap = A; int kk = kt;
        if (A2 != nullptr && kt >= KA) { Ap = A2; kk = kt - KA; }
        #pragma unroll
        for (int c = 0; c < 2; ++c) {
            int r = wave * 32 + c * 16;                       // wave-uniform tile row base
            gload16(Ap + (size_t)(bm + r + lrow) * lda + kk + lcol, &sA[r * 32]);
        }
        #pragma unroll
        for (int c = 0; c < 2; ++c) {
            int r = wave * 32 + c * 16;
            gload16(W + (size_t)(bn + r + lrow) * ldw + kt + lcol, &sB[r * 32]);
        }
        __syncthreads();                                      // compiler drains vmcnt here
        short8 af[4], bf[4];
        #pragma unroll
        for (int mt = 0; mt < 4; ++mt)
            af[mt] = *(const short8*)&sA[(wm * 64 + mt * 16 + l16) * 32 + quad * 8];
        #pragma unroll
        for (int nt = 0; nt < 4; ++nt)
            bf[nt] = *(const short8*)&sB[(wn * 64 + nt * 16 + l16) * 32 + quad * 8];
        #pragma unroll
        for (int mt = 0; mt < 4; ++mt)
            #pragma unroll
            for (int nt = 0; nt < 4; ++nt)
                acc[mt][nt] = __builtin_amdgcn_mfma_f32_16x16x32_bf16(af[mt], bf[nt], acc[mt][nt], 0, 0, 0);
        __syncthreads();
    }

    // epilogue: C/D col = lane&15, row = quad*4 + reg
    #pragma unroll
    for (int nt = 0; nt < 4; ++nt) {
        int gn = bn + wn * 64 + nt * 16 + l16;                // < N (N % 128 == 0)
        float bv = (bias != nullptr) ? bf2f(bias[gn]) : 0.0f;
        #pragma unroll
        for (int mt = 0; mt < 4; ++mt) {
            #pragma unroll
            for (int r = 0; r < 4; ++r) {
                int gm = bm + wm * 64 + mt * 16 + quad * 4 + r;
                if (gm < M) {
                    float v = acc[mt][nt][r] + bv;
                    if (act) v = v > 0.0f ? v : 0.1f * v;
                    if (outf != nullptr) outf[(size_t)gm * ldo + gn] = v;
                    else out[(size_t)gm * ldo + gn] = f2bf(v);
                }
            }
        }
    }
}

// ---------------- generic bf16 MFMA GEMM (init path: odd K/N shapes) ----------
template<int NT>
__global__ __launch_bounds__(256) void gemm_kernel(
    const void* A, const void* A2, int KA, int lda, const int* dflag,
    const u16* W, int ldw, const u16* bias,
    u16* out, float* outf, int ldo,
    const u16* addsrc,
    int M, int N, int K, int act)
{
    __shared__ __align__(16) u16 sA[64][40];
    __shared__ __align__(16) u16 sB[NT * 16][40];
    const int t = threadIdx.x;
    const int wave = t >> 6, lane = t & 63;
    const int quad = lane >> 4, l16 = lane & 15;
    const int bm = blockIdx.y * 64, bn = blockIdx.x * (NT * 16);
    const bool af32 = (dflag != nullptr) && (*dflag != 0);

    floatx4 acc[NT];
    #pragma unroll
    for (int i = 0; i < NT; ++i) acc[i] = (floatx4){0.f, 0.f, 0.f, 0.f};

    for (int kt = 0; kt < K; kt += 32) {
        #pragma unroll
        for (int it = 0; it < 2; ++it) {
            int i4 = t + it * 256;
            int row = i4 >> 3;
            int c4 = (i4 & 7) << 2;
            int gm = bm + row;
            int gk = kt + c4;
            ushort4 tv;
            bool inA2 = (A2 != nullptr) && (gk >= KA);
            if (gm < M && gk + 4 <= K) {
                if (inA2) {
                    tv = *(const ushort4*)((const u16*)A2 + (size_t)gm * lda + (gk - KA));
                } else if (af32) {
                    float4 fv = *(const float4*)((const float*)A + (size_t)gm * lda + gk);
                    tv.x = f2bf(fv.x); tv.y = f2bf(fv.y); tv.z = f2bf(fv.z); tv.w = f2bf(fv.w);
                } else {
                    tv = *(const ushort4*)((const u16*)A + (size_t)gm * lda + gk);
                }
            } else {
                u16 tmp[4];
                for (int j = 0; j < 4; ++j) {
                    int gkj = gk + j; u16 x = 0;
                    if (gm < M && gkj < K) {
                        if (A2 != nullptr && gkj >= KA)
                            x = ((const u16*)A2)[(size_t)gm * lda + (gkj - KA)];
                        else if (af32)
                            x = f2bf(((const float*)A)[(size_t)gm * lda + gkj]);
                        else
                            x = ((const u16*)A)[(size_t)gm * lda + gkj];
                    }
                    tmp[j] = x;
                }
                tv.x = tmp[0]; tv.y = tmp[1]; tv.z = tmp[2]; tv.w = tmp[3];
            }
            *(ushort4*)&sA[row][c4] = tv;
        }
        #pragma unroll
        for (int it = 0; it < NT / 2; ++it) {
            int i4 = t + it * 256;
            int row = i4 >> 3;
            int c4 = (i4 & 7) << 2;
            int gn = bn + row;
            int gk = kt + c4;
            ushort4 tv;
            if (gn < N && gk + 4 <= K) {
                tv = *(const ushort4*)(W + (size_t)gn * ldw + gk);
            } else {
                u16 tmp[4];
                for (int j = 0; j < 4; ++j)
                    tmp[j] = (gn < N && gk + j < K) ? W[(size_t)gn * ldw + gk + j] : (u16)0;
                tv.x = tmp[0]; tv.y = tmp[1]; tv.z = tmp[2]; tv.w = tmp[3];
            }
            *(ushort4*)&sB[row][c4] = tv;
        }
        __syncthreads();
        short8 af = *(const short8*)&sA[wave * 16 + l16][quad * 8];
        #pragma unroll
        for (int nt = 0; nt < NT; ++nt) {
            short8 bf = *(const short8*)&sB[nt * 16 + l16][quad * 8];
            acc[nt] = __builtin_amdgcn_mfma_f32_16x16x32_bf16(af, bf, acc[nt], 0, 0, 0);
        }
        __syncthreads();
    }

    #pragma unroll
    for (int nt = 0; nt < NT; ++nt) {
        int gn = bn + nt * 16 + l16;
        if (gn >= N) continue;
        float bv = (bias != nullptr) ? bf2f(bias[gn]) : 0.0f;
        #pragma unroll
        for (int r = 0; r < 4; ++r) {
            int gm = bm + wave * 16 + quad * 4 + r;
            if (gm < M) {
                float v = acc[nt][r] + bv;
                if (act) v = v > 0.0f ? v : 0.1f * v;
                if (addsrc != nullptr) v += bf2f(addsrc[(size_t)gm * ldo + gn]);
                if (outf != nullptr) outf[(size_t)gm * ldo + gn] = v;
                else out[(size_t)gm * ldo + gn] = f2bf(v);
            }
        }
    }
}

// ---------------- neighbor-mean aggregation (pull, CSR) ----------------
__global__ __launch_bounds__(256) void agg_kernel(
    const u16* h, const int* row_start, const int* esrc,
    const float* inv_w, u16* out)
{
    int gid = blockIdx.x * blockDim.x + threadIdx.x;
    int wid = gid >> 6;
    int lane = gid & 63;
    if (wid >= NNODES) return;
    int e0 = row_start[wid], e1 = row_start[wid + 1];
    e0 = max(0, min(e0, NEDGES));
    e1 = max(e0, min(e1, NEDGES));
    float a0 = 0.f, a1 = 0.f, a2 = 0.f, a3 = 0.f;
    for (int e = e0; e < e1; ++e) {
        int u = esrc[e];
        if ((unsigned)u >= (unsigned)NNODES) u = 0;
        ushort4 tv = *(const ushort4*)(h + (size_t)u * FD + lane * 4);
        a0 += bf2f(tv.x); a1 += bf2f(tv.y); a2 += bf2f(tv.z); a3 += bf2f(tv.w);
    }
    float s = inv_w[wid];
    ushort4 ov;
    ov.x = f2bf(a0 * s); ov.y = f2bf(a1 * s); ov.z = f2bf(a2 * s); ov.w = f2bf(a3 * s);
    *(ushort4*)(out + (size_t)wid * FD + lane * 4) = ov;
}

// ------------- bf16 row lrelu + L2 normalize (in-place safe) -------------
__global__ __launch_bounds__(256) void norm_kernel(const u16* in, u16* out, int act)
{
    int gid = blockIdx.x * blockDim.x + threadIdx.x;
    int wid = gid >> 6, lane = gid & 63;
    if (wid >= NNODES) return;
    ushort4 tv = *(const ushort4*)(in + (size_t)wid * FD + lane * 4);
    u16 raw[4] = {tv.x, tv.y, tv.z, tv.w};
    float f[4]; float ss = 0.f;
    #pragma unroll
    for (int j = 0; j < 4; ++j) {
        float x = bf2f(raw[j]);
        if (act) x = x > 0.f ? x : 0.1f * x;
        f[j] = x; ss += x * x;
    }
    #pragma unroll
    for (int off = 32; off > 0; off >>= 1) ss += __shfl_xor(ss, off);
    float s = 1.0f / fmaxf(sqrtf(ss), 1e-6f);
    ushort4 ov;
    ov.x = f2bf(f[0] * s); ov.y = f2bf(f[1] * s);
    ov.z = f2bf(f[2] * s); ov.w = f2bf(f[3] * s);
    *(ushort4*)(out + (size_t)wid * FD + lane * 4) = ov;
}

// ------------- f32 final L2 normalize, in place on d_out -------------
__global__ __launch_bounds__(256) void normf_kernel(float* io)
{
    int gid = blockIdx.x * blockDim.x + threadIdx.x;
    int wid = gid >> 6, lane = gid & 63;
    if (wid >= NNODES) return;
    float4 v = *(float4*)(io + (size_t)wid * FD + lane * 4);
    float ss = v.x * v.x + v.y * v.y + v.z * v.z + v.w * v.w;
    #pragma unroll
    for (int off = 32; off > 0; off >>= 1) ss += __shfl_xor(ss, off);
    float s = 1.0f / fmaxf(sqrtf(ss), 1e-6f);
    v.x *= s; v.y *= s; v.z *= s; v.w *= s;
    *(float4*)(io + (size_t)wid * FD + lane * 4) = v;
}

extern "C" void kernel_launch(void* const* d_in, const int* in_sizes, int n_in,
                              void* d_out, int out_size, void* d_ws, size_t ws_size,
                              hipStream_t stream) {
    const void* content = d_in[1];
    const int* src      = (const int*)d_in[2];
    const int* dst      = (const int*)d_in[3];
    const void* emb     = d_in[4];

    // ---- workspace layout (~57.7 MB) ----
    char* ws = (char*)d_ws;
    u16* arena = (u16*)(ws);                       // 1,682,304 B weights/biases bf16
    u16* hbuf  = (u16*)(ws + 1682432);             // 25.6 MB
    u16* buf2  = (u16*)(ws + 27282432);            // 25.6 MB (h_agg / Wo1-out)
    u16* cbuf  = (u16*)(ws + 27282432);            // 30.4 MB init-only c (sequenced before CSR)
    int*   deg    = (int*)(ws + 52882432);
    int*   rs     = (int*)(ws + 53082624);
    int*   cursor = (int*)(ws + 53282816);
    float* inv_w  = (float*)(ws + 53483008);
    int*   esrc   = (int*)(ws + 53683200);         // 4 MB, ends 57,683,200
    int*   flag   = (int*)(ws + 57683200);
    int*   bsum   = (int*)(ws + 57683456);         // NSCAN ints

    u16* aWexp  = arena;            u16* aBexp  = arena + 16384;
    u16* aWp1   = arena + 16640;    u16* aBp1   = arena + 106640;
    u16* aWp2   = arena + 106944;   u16* aBp2   = arena + 183744;
    u16* aWconv = arena + 184000;   u16* aBconv = arena + 577216;
    u16* aWo1   = arena + 577984;   u16* aBo1   = arena + 709056;
    u16* aWo2   = arena + 709568;   u16* aBo2   = arena + 840640;

    const int MB64  = (NNODES + 63) / 64;    // 782
    const int MB128 = (NNODES + 127) / 128;  // 391
    dim3 blk(256);

    // ---- dtype probe + weight conversion ----
    detect_kernel<<<1, 256, 0, stream>>>((const u16*)content, flag);
    convert_kernel<<<(841152 + 255) / 256, 256, 0, stream>>>(arena, flag,
        d_in[5], d_in[6], d_in[7], d_in[8], d_in[9], d_in[10], d_in[11],
        d_in[12], d_in[13], d_in[14], d_in[15], d_in[16]);

    // ---- init GEMMs (generic kernel; cbuf overlaps CSR region, sequenced) ----
    gemm_kernel<4><<<dim3(FD / 64, MB64), blk, 0, stream>>>(emb, nullptr, 0, EDIM, flag,
        aWexp, EDIM, aBexp, hbuf, nullptr, FD, nullptr, NNODES, FD, EDIM, 1);
    gemm_kernel<4><<<dim3((NCD + 63) / 64, MB64), blk, 0, stream>>>(content, nullptr, 0, NCD, flag,
        aWp1, NCD, aBp1, cbuf, nullptr, NCP, nullptr, NNODES, NCD, NCD, 1);
    gemm_kernel<4><<<dim3(FD / 64, MB64), blk, 0, stream>>>(cbuf, nullptr, 0, NCP, nullptr,
        aWp2, NCD, aBp2, hbuf, nullptr, FD, hbuf, NNODES, FD, NCD, 1);

    // ---- CSR by destination (multi-block scan) ----
    hipMemsetAsync(deg, 0, (size_t)NNODES * 4, stream);
    count_kernel<<<(NEDGES + 255) / 256, 256, 0, stream>>>(dst, deg);
    scan1_kernel<<<NSCAN, 256, 0, stream>>>(deg, bsum);
    scan2_kernel<<<1, 256, 0, stream>>>(bsum, rs);
    scan3_kernel<<<NSCAN, 256, 0, stream>>>(deg, bsum, rs, cursor, inv_w);
    fill_kernel<<<(NEDGES + 255) / 256, 256, 0, stream>>>(src, dst, cursor, esrc);

    // ---- layers ----
    for (int i = 0; i < 3; ++i) {
        agg_kernel<<<(NNODES * 64) / 256, blk, 0, stream>>>(hbuf, rs, esrc, inv_w, buf2);
        if (i < 2) {
            // h_new = [h | h_agg] @ W_conv[i]^T + b  (K=512), in place into hbuf
            gemm128_kernel<<<dim3(FD / 128, MB128), blk, 0, stream>>>(hbuf, buf2, FD, FD,
                aWconv + (size_t)i * FD * 2 * FD, 2 * FD, aBconv + (size_t)i * FD,
                hbuf, nullptr, FD, NNODES, FD, 2 * FD, 0);
            norm_kernel<<<(NNODES * 64) / 256, blk, 0, stream>>>(hbuf, hbuf, 1);
            gemm128_kernel<<<dim3(FD / 128, MB128), blk, 0, stream>>>(hbuf, nullptr, 0, FD,
                aWo1 + (size_t)i * FD * FD, FD, aBo1 + (size_t)i * FD,
                buf2, nullptr, FD, NNODES, FD, FD, 1);
            gemm128_kernel<<<dim3(FD / 128, MB128), blk, 0, stream>>>(buf2, nullptr, 0, FD,
                aWo2 + (size_t)i * FD * FD, FD, aBo2 + (size_t)i * FD,
                hbuf, nullptr, FD, NNODES, FD, FD, 0);
        } else {
            gemm128_kernel<<<dim3(FD / 128, MB128), blk, 0, stream>>>(hbuf, buf2, FD, FD,
                aWconv + (size_t)i * FD * 2 * FD, 2 * FD, aBconv + (size_t)i * FD,
                nullptr, (float*)d_out, FD, NNODES, FD, 2 * FD, 0);
            normf_kernel<<<(NNODES * 64) / 256, blk, 0, stream>>>((float*)d_out);
        }
    }
}

// Round 5
// 1037.299 us; speedup vs baseline: 1.4768x; 1.0209x over previous
//
#include <hip/hip_runtime.h>
#include <stdint.h>

#define NNODES 50000
#define NROWS_PAD 50048            // 391 * 128
#define NEDGES 1000000
#define FD 256
#define NCPAD 384                  // padded content/proj1 dims (3*128, mult of 32)
#define EDIM 64
#define NSCAN ((NNODES + 255) / 256)   // 196 scan blocks

typedef unsigned short u16;
typedef __attribute__((ext_vector_type(8))) short short8;   // 8 x bf16 bits (MFMA A/B frag)
typedef __attribute__((ext_vector_type(4))) float floatx4;

__device__ __forceinline__ float bf2f(u16 x) {
    union { unsigned u; float f; } c; c.u = ((unsigned)x) << 16; return c.f;
}
__device__ __forceinline__ u16 f2bf(float f) {
    union { float f; unsigned u; } c; c.f = f;
    unsigned u = c.u;
    return (u16)((u + 0x7fffu + ((u >> 16) & 1u)) >> 16);   // round-to-nearest-even
}
// async global->LDS, 16B per lane; LDS dest = wave-uniform base + lane*16 (m97 pattern)
__device__ __forceinline__ void gload16(const u16* g, u16* l) {
    __builtin_amdgcn_global_load_lds(
        (const __attribute__((address_space(1))) void*)g,
        (__attribute__((address_space(3))) void*)l, 16, 0, 0);
}

// ---------- runtime input-dtype probe (f32 vs bf16 harness feed) ----------
__global__ void detect_kernel(const u16* p, int* flag) {
    __shared__ int smax;
    if (threadIdx.x == 0) smax = 0;
    __syncthreads();
    int m = 0;
    for (int i = threadIdx.x; i < 8192; i += 256) {
        int e = (p[i] >> 7) & 0xFF;
        m = m > e ? m : e;
    }
    atomicMax(&smax, m);
    __syncthreads();
    if (threadIdx.x == 0) *flag = (smax >= 140) ? 1 : 0;
}

// ---------- weights/biases -> padded bf16 arena (920192 elements) ----------
// table: {dst_off, rows_real, cols_real, cols_pad}; rows beyond rows_real and
// cols beyond cols_real are zero.
__global__ void convert_kernel(u16* arena, const int* flagp,
    const void* wexp, const void* bexp, const void* wp1, const void* bp1,
    const void* wp2, const void* bp2, const void* wconv, const void* bconv,
    const void* wo1, const void* bo1, const void* wo2, const void* bo2)
{
    const int offs[13]  = {0,16384,16640,164096,164480,262784,263040,
                           656256,657024,788096,788608,919680,920192};
    const int rreal[12] = {256,1,300,1,256,1,768,1,512,1,512,1};
    const int creal[12] = {64,256,300,300,300,256,512,768,256,512,256,512};
    const int cpad[12]  = {64,256,384,384,384,256,512,768,256,512,256,512};
    long gid = (long)blockIdx.x * 256 + threadIdx.x;
    if (gid >= 920192) return;
    const void* srcs[12] = {wexp,bexp,wp1,bp1,wp2,bp2,wconv,bconv,wo1,bo1,wo2,bo2};
    int fl = *flagp;
    int t = 0;
    #pragma unroll
    for (int i = 1; i < 12; ++i) if (gid >= offs[i]) t = i;
    long local = gid - offs[t];
    int r = (int)(local / cpad[t]);
    int c = (int)(local % cpad[t]);
    u16 v = 0;
    if (r < rreal[t] && c < creal[t]) {
        long si = (long)r * creal[t] + c;
        v = fl ? f2bf(((const float*)srcs[t])[si]) : ((const u16*)srcs[t])[si];
    }
    arena[gid] = v;
}

// ---------- input pad/convert: [rows_real x cols_real] -> bf16 [.. x CP] ------
template<int CP>
__global__ void pad2d_kernel(u16* dst, const void* src, int rows_real,
                             int cols_real, long total, const int* flagp)
{
    long gid = (long)blockIdx.x * 256 + threadIdx.x;
    if (gid >= total) return;
    int r = (int)(gid / CP);
    int c = (int)(gid % CP);
    u16 v = 0;
    if (r < rows_real && c < cols_real) {
        long si = (long)r * cols_real + c;
        v = (*flagp) ? f2bf(((const float*)src)[si]) : ((const u16*)src)[si];
    }
    dst[gid] = v;
}

// ---------------- CSR build ----------------
__global__ void count_kernel(const int* dst, int* deg) {
    int e = blockIdx.x * blockDim.x + threadIdx.x;
    if (e < NEDGES) atomicAdd(&deg[dst[e]], 1);
}

__global__ __launch_bounds__(256) void scan1_kernel(const int* deg, int* bsum) {
    __shared__ int s[256];
    int t = threadIdx.x;
    int i = blockIdx.x * 256 + t;
    s[t] = (i < NNODES) ? deg[i] : 0;
    __syncthreads();
    #pragma unroll
    for (int off = 128; off > 0; off >>= 1) {
        if (t < off) s[t] += s[t + off];
        __syncthreads();
    }
    if (t == 0) bsum[blockIdx.x] = s[0];
}

__global__ __launch_bounds__(256) void scan2_kernel(int* bsum, int* row_start) {
    __shared__ int s[256];
    int t = threadIdx.x;
    int v = (t < NSCAN) ? bsum[t] : 0;
    s[t] = v;
    __syncthreads();
    for (int off = 1; off < 256; off <<= 1) {
        int x = (t >= off) ? s[t - off] : 0;
        __syncthreads();
        s[t] += x;
        __syncthreads();
    }
    if (t < NSCAN) bsum[t] = s[t] - v;   // exclusive
    if (t == 0) row_start[NNODES] = NEDGES;
}

__global__ __launch_bounds__(256) void scan3_kernel(const int* deg, const int* bsum,
        int* row_start, int* cursor, float* inv_w) {
    __shared__ int s[256];
    int t = threadIdx.x;
    int i = blockIdx.x * 256 + t;
    int v = (i < NNODES) ? deg[i] : 0;
    s[t] = v;
    __syncthreads();
    for (int off = 1; off < 256; off <<= 1) {
        int x = (t >= off) ? s[t - off] : 0;
        __syncthreads();
        s[t] += x;
        __syncthreads();
    }
    if (i < NNODES) {
        int base = bsum[blockIdx.x] + s[t] - v;
        row_start[i] = base;
        cursor[i] = base;
        inv_w[i] = 1.0f / (float)(v > 0 ? v : 1);
    }
}

__global__ void fill_kernel(const int* src, const int* dst, int* cursor, int* esrc) {
    int e = blockIdx.x * blockDim.x + threadIdx.x;
    if (e < NEDGES) {
        int v = dst[e];
        int pos = atomicAdd(&cursor[v], 1);
        if ((unsigned)pos < (unsigned)NEDGES) esrc[pos] = src[e];
    }
}

// -------- 128x128 MFMA GEMM (m97 structure): out = act(A @ W^T + b) (+addsrc) --
// Requires: N mult of 128, K mult of 32, KA mult of 32. A rows over-read to
// bm+127 (must be allocated); garbage rows never stored (C row m <- A row m only).
// out must NOT alias A (grid.x > 1 blocks share A rows). addsrc==out is safe.
__global__ __launch_bounds__(256) void gemm128_kernel(
    const u16* A, const u16* A2, int KA, int lda,
    const u16* W, int ldw, const u16* bias,
    u16* out, float* outf, int ldo, const u16* addsrc,
    int M, int N, int K, int act)
{
    __shared__ __align__(16) u16 sA[128 * 32];   // [row][k] pitch 32 (gload16 layout)
    __shared__ __align__(16) u16 sB[128 * 32];
    const int t = threadIdx.x;
    const int wave = t >> 6, lane = t & 63;
    const int quad = lane >> 4, l16 = lane & 15;
    const int wm = wave >> 1, wn = wave & 1;
    const int bm = blockIdx.y * 128, bn = blockIdx.x * 128;
    const int lrow = lane >> 2;          // 0..15
    const int lcol = (lane & 3) * 8;     // 0,8,16,24

    floatx4 acc[4][4];
    #pragma unroll
    for (int i = 0; i < 4; ++i)
        #pragma unroll
        for (int j = 0; j < 4; ++j) acc[i][j] = (floatx4){0.f, 0.f, 0.f, 0.f};

    for (int kt = 0; kt < K; kt += 32) {
        const u16* Ap = A; int kk = kt;
        if (A2 != nullptr && kt >= KA) { Ap = A2; kk = kt - KA; }
        #pragma unroll
        for (int c = 0; c < 2; ++c) {
            int r = wave * 32 + c * 16;                       // wave-uniform tile row base
            gload16(Ap + (size_t)(bm + r + lrow) * lda + kk + lcol, &sA[r * 32]);
        }
        #pragma unroll
        for (int c = 0; c < 2; ++c) {
            int r = wave * 32 + c * 16;
            gload16(W + (size_t)(bn + r + lrow) * ldw + kt + lcol, &sB[r * 32]);
        }
        __syncthreads();
        short8 af[4], bf[4];
        #pragma unroll
        for (int mt = 0; mt < 4; ++mt)
            af[mt] = *(const short8*)&sA[(wm * 64 + mt * 16 + l16) * 32 + quad * 8];
        #pragma unroll
        for (int nt = 0; nt < 4; ++nt)
            bf[nt] = *(const short8*)&sB[(wn * 64 + nt * 16 + l16) * 32 + quad * 8];
        #pragma unroll
        for (int mt = 0; mt < 4; ++mt)
            #pragma unroll
            for (int nt = 0; nt < 4; ++nt)
                acc[mt][nt] = __builtin_amdgcn_mfma_f32_16x16x32_bf16(af[mt], bf[nt], acc[mt][nt], 0, 0, 0);
        __syncthreads();
    }

    // epilogue: C/D col = lane&15, row = quad*4 + reg (HW-verified)
    #pragma unroll
    for (int nt = 0; nt < 4; ++nt) {
        int gn = bn + wn * 64 + nt * 16 + l16;                // < N (N % 128 == 0)
        float bv = (bias != nullptr) ? bf2f(bias[gn]) : 0.0f;
        #pragma unroll
        for (int mt = 0; mt < 4; ++mt) {
            #pragma unroll
            for (int r = 0; r < 4; ++r) {
                int gm = bm + wm * 64 + mt * 16 + quad * 4 + r;
                if (gm < M) {
                    float v = acc[mt][nt][r] + bv;
                    if (act) v = v > 0.0f ? v : 0.1f * v;
                    if (addsrc != nullptr) v += bf2f(addsrc[(size_t)gm * ldo + gn]);
                    if (outf != nullptr) outf[(size_t)gm * ldo + gn] = v;
                    else out[(size_t)gm * ldo + gn] = f2bf(v);
                }
            }
        }
    }
}

// ---------------- neighbor-mean aggregation (pull, CSR) ----------------
__global__ __launch_bounds__(256) void agg_kernel(
    const u16* h, const int* row_start, const int* esrc,
    const float* inv_w, u16* out)
{
    int gid = blockIdx.x * blockDim.x + threadIdx.x;
    int wid = gid >> 6;
    int lane = gid & 63;
    if (wid >= NNODES) return;
    int e0 = row_start[wid], e1 = row_start[wid + 1];
    e0 = max(0, min(e0, NEDGES));
    e1 = max(e0, min(e1, NEDGES));
    float a0 = 0.f, a1 = 0.f, a2 = 0.f, a3 = 0.f;
    for (int e = e0; e < e1; ++e) {
        int u = esrc[e];
        if ((unsigned)u >= (unsigned)NNODES) u = 0;
        ushort4 tv = *(const ushort4*)(h + (size_t)u * FD + lane * 4);
        a0 += bf2f(tv.x); a1 += bf2f(tv.y); a2 += bf2f(tv.z); a3 += bf2f(tv.w);
    }
    float s = inv_w[wid];
    ushort4 ov;
    ov.x = f2bf(a0 * s); ov.y = f2bf(a1 * s); ov.z = f2bf(a2 * s); ov.w = f2bf(a3 * s);
    *(ushort4*)(out + (size_t)wid * FD + lane * 4) = ov;
}

// ------------- bf16 row lrelu + L2 normalize (in-place safe) -------------
__global__ __launch_bounds__(256) void norm_kernel(const u16* in, u16* out, int act)
{
    int gid = blockIdx.x * blockDim.x + threadIdx.x;
    int wid = gid >> 6, lane = gid & 63;
    if (wid >= NNODES) return;
    ushort4 tv = *(const ushort4*)(in + (size_t)wid * FD + lane * 4);
    u16 raw[4] = {tv.x, tv.y, tv.z, tv.w};
    float f[4]; float ss = 0.f;
    #pragma unroll
    for (int j = 0; j < 4; ++j) {
        float x = bf2f(raw[j]);
        if (act) x = x > 0.f ? x : 0.1f * x;
        f[j] = x; ss += x * x;
    }
    #pragma unroll
    for (int off = 32; off > 0; off >>= 1) ss += __shfl_xor(ss, off);
    float s = 1.0f / fmaxf(sqrtf(ss), 1e-6f);
    ushort4 ov;
    ov.x = f2bf(f[0] * s); ov.y = f2bf(f[1] * s);
    ov.z = f2bf(f[2] * s); ov.w = f2bf(f[3] * s);
    *(ushort4*)(out + (size_t)wid * FD + lane * 4) = ov;
}

// ------------- f32 final L2 normalize, in place on d_out -------------
__global__ __launch_bounds__(256) void normf_kernel(float* io)
{
    int gid = blockIdx.x * blockDim.x + threadIdx.x;
    int wid = gid >> 6, lane = gid & 63;
    if (wid >= NNODES) return;
    float4 v = *(float4*)(io + (size_t)wid * FD + lane * 4);
    float ss = v.x * v.x + v.y * v.y + v.z * v.z + v.w * v.w;
    #pragma unroll
    for (int off = 32; off > 0; off >>= 1) ss += __shfl_xor(ss, off);
    float s = 1.0f / fmaxf(sqrtf(ss), 1e-6f);
    v.x *= s; v.y *= s; v.z *= s; v.w *= s;
    *(float4*)(io + (size_t)wid * FD + lane * 4) = v;
}

extern "C" void kernel_launch(void* const* d_in, const int* in_sizes, int n_in,
                              void* d_out, int out_size, void* d_ws, size_t ws_size,
                              hipStream_t stream) {
    const void* content = d_in[1];
    const int* src      = (const int*)d_in[2];
    const int* dst      = (const int*)d_in[3];
    const void* emb     = d_in[4];

    // ---- workspace layout (~83.5 MB peak, aliased; all offsets 256B-aligned) --
    char* ws = (char*)d_ws;
    u16* arena = (u16*)(ws);                        // 1,840,384 B padded weights
    u16* hbuf  = (u16*)(ws + 1840640);              // [50048 x 256] bf16
    u16* buf2  = (u16*)(ws + 27465216);             // [50048 x 256] (h_agg / Wo1-out)
    u16* buf3  = (u16*)(ws + 53089792);             // [50048 x 256] (conv out)
    u16* cpad  = (u16*)(ws + 27465216);             // content_pad [50048 x 384], aliases buf2+buf3 head (init only)
    u16* ebuf  = (u16*)(ws + 65902336);             // emb bf16 [50048 x 64], inside buf3 tail (init only)
    int*   deg    = (int*)(ws + 78714368);
    int*   rs     = (int*)(ws + 78914560);
    int*   cursor = (int*)(ws + 79114752);
    float* inv_w  = (float*)(ws + 79314944);
    int*   esrc   = (int*)(ws + 79515136);          // 4 MB
    int*   bsum   = (int*)(ws + 83515648);
    int*   flag   = (int*)(ws + 83516672);
    u16* cbuf  = (u16*)d_out;                       // c [50048 x 384] bf16 in d_out (38.4 of 51.2 MB; init only)

    // arena offsets (elements; see convert_kernel table)
    u16* aWexp  = arena;            u16* aBexp  = arena + 16384;
    u16* aWp1   = arena + 16640;    u16* aBp1   = arena + 164096;
    u16* aWp2   = arena + 164480;   u16* aBp2   = arena + 262784;
    u16* aWconv = arena + 263040;   u16* aBconv = arena + 656256;
    u16* aWo1   = arena + 657024;   u16* aBo1   = arena + 788096;
    u16* aWo2   = arena + 788608;   u16* aBo2   = arena + 919680;

    const int MB128 = NROWS_PAD / 128;  // 391
    dim3 blk(256);

    // ---- dtype probe + weight conversion/padding ----
    detect_kernel<<<1, 256, 0, stream>>>((const u16*)content, flag);
    convert_kernel<<<(920192 + 255) / 256, 256, 0, stream>>>(arena, flag,
        d_in[5], d_in[6], d_in[7], d_in[8], d_in[9], d_in[10], d_in[11],
        d_in[12], d_in[13], d_in[14], d_in[15], d_in[16]);
    // pad inputs to bf16 MFMA-friendly shapes
    {
        long tot_c = (long)NROWS_PAD * NCPAD;
        pad2d_kernel<NCPAD><<<(int)((tot_c + 255) / 256), 256, 0, stream>>>(
            cpad, content, NNODES, 300, tot_c, flag);
        long tot_e = (long)NROWS_PAD * EDIM;
        pad2d_kernel<EDIM><<<(int)((tot_e + 255) / 256), 256, 0, stream>>>(
            ebuf, emb, NNODES, EDIM, tot_e, flag);
    }

    // ---- init GEMMs (all gemm128) ----
    // h = lrelu(emb @ W_exp^T + b_exp)
    gemm128_kernel<<<dim3(2, MB128), blk, 0, stream>>>(ebuf, nullptr, 0, EDIM,
        aWexp, EDIM, aBexp, hbuf, nullptr, FD, nullptr, NNODES, FD, EDIM, 1);
    // c = lrelu(content_pad @ W_p1^T + b_p1)   (N=K=384 padded) -> d_out region
    gemm128_kernel<<<dim3(3, MB128), blk, 0, stream>>>(cpad, nullptr, 0, NCPAD,
        aWp1, NCPAD, aBp1, cbuf, nullptr, NCPAD, nullptr, NNODES, NCPAD, NCPAD, 1);
    // h = lrelu(c @ W_p2^T + b_p2) + h   (addsrc == out: same-thread read-then-write)
    gemm128_kernel<<<dim3(2, MB128), blk, 0, stream>>>(cbuf, nullptr, 0, NCPAD,
        aWp2, NCPAD, aBp2, hbuf, nullptr, FD, hbuf, NNODES, FD, NCPAD, 1);

    // ---- CSR by destination ----
    hipMemsetAsync(deg, 0, (size_t)NNODES * 4, stream);
    count_kernel<<<(NEDGES + 255) / 256, 256, 0, stream>>>(dst, deg);
    scan1_kernel<<<NSCAN, 256, 0, stream>>>(deg, bsum);
    scan2_kernel<<<1, 256, 0, stream>>>(bsum, rs);
    scan3_kernel<<<NSCAN, 256, 0, stream>>>(deg, bsum, rs, cursor, inv_w);
    fill_kernel<<<(NEDGES + 255) / 256, 256, 0, stream>>>(src, dst, cursor, esrc);

    // ---- layers (ping-pong: conv->buf3, Wo1->buf2, Wo2->hbuf; no in-place GEMM) --
    for (int i = 0; i < 3; ++i) {
        agg_kernel<<<(NNODES * 64) / 256, blk, 0, stream>>>(hbuf, rs, esrc, inv_w, buf2);
        if (i < 2) {
            gemm128_kernel<<<dim3(2, MB128), blk, 0, stream>>>(hbuf, buf2, FD, FD,
                aWconv + (size_t)i * FD * 2 * FD, 2 * FD, aBconv + (size_t)i * FD,
                buf3, nullptr, FD, nullptr, NNODES, FD, 2 * FD, 0);
            norm_kernel<<<(NNODES * 64) / 256, blk, 0, stream>>>(buf3, buf3, 1);
            gemm128_kernel<<<dim3(2, MB128), blk, 0, stream>>>(buf3, nullptr, 0, FD,
                aWo1 + (size_t)i * FD * FD, FD, aBo1 + (size_t)i * FD,
                buf2, nullptr, FD, nullptr, NNODES, FD, FD, 1);
            gemm128_kernel<<<dim3(2, MB128), blk, 0, stream>>>(buf2, nullptr, 0, FD,
                aWo2 + (size_t)i * FD * FD, FD, aBo2 + (size_t)i * FD,
                hbuf, nullptr, FD, nullptr, NNODES, FD, FD, 0);
        } else {
            gemm128_kernel<<<dim3(2, MB128), blk, 0, stream>>>(hbuf, buf2, FD, FD,
                aWconv + (size_t)i * FD * 2 * FD, 2 * FD, aBconv + (size_t)i * FD,
                nullptr, (float*)d_out, FD, nullptr, NNODES, FD, 2 * FD, 0);
            normf_kernel<<<(NNODES * 64) / 256, blk, 0, stream>>>((float*)d_out);
        }
    }
}

// Round 6
// 907.166 us; speedup vs baseline: 1.6886x; 1.1435x over previous
//
#include <hip/hip_runtime.h>
#include <stdint.h>

#define NNODES 50000
#define NROWS_PAD 50048            // 391 * 128
#define NEDGES 1000000
#define FD 256
#define NCPAD 384                  // padded content/proj1 dims (3*128, mult of 64)
#define EDIM 64
#define NSCAN ((NNODES + 255) / 256)   // 196 scan blocks

typedef unsigned short u16;
typedef __attribute__((ext_vector_type(8))) short short8;   // 8 x bf16 bits (MFMA A/B frag)
typedef __attribute__((ext_vector_type(4))) float floatx4;

__device__ __forceinline__ float bf2f(u16 x) {
    union { unsigned u; float f; } c; c.u = ((unsigned)x) << 16; return c.f;
}
__device__ __forceinline__ u16 f2bf(float f) {
    union { float f; unsigned u; } c; c.f = f;
    unsigned u = c.u;
    return (u16)((u + 0x7fffu + ((u >> 16) & 1u)) >> 16);   // round-to-nearest-even
}
// async global->LDS, 16B per lane; LDS dest = wave-uniform base + lane*16 (m97 pattern)
__device__ __forceinline__ void gload16(const u16* g, u16* l) {
    __builtin_amdgcn_global_load_lds(
        (const __attribute__((address_space(1))) void*)g,
        (__attribute__((address_space(3))) void*)l, 16, 0, 0);
}

// ---------- runtime input-dtype probe (f32 vs bf16 harness feed) ----------
__global__ void detect_kernel(const u16* p, int* flag) {
    __shared__ int smax;
    if (threadIdx.x == 0) smax = 0;
    __syncthreads();
    int m = 0;
    for (int i = threadIdx.x; i < 8192; i += 256) {
        int e = (p[i] >> 7) & 0xFF;
        m = m > e ? m : e;
    }
    atomicMax(&smax, m);
    __syncthreads();
    if (threadIdx.x == 0) *flag = (smax >= 140) ? 1 : 0;
}

// ---------- weights/biases -> padded bf16 arena (920192 elements) ----------
__global__ void convert_kernel(u16* arena, const int* flagp,
    const void* wexp, const void* bexp, const void* wp1, const void* bp1,
    const void* wp2, const void* bp2, const void* wconv, const void* bconv,
    const void* wo1, const void* bo1, const void* wo2, const void* bo2)
{
    const int offs[13]  = {0,16384,16640,164096,164480,262784,263040,
                           656256,657024,788096,788608,919680,920192};
    const int rreal[12] = {256,1,300,1,256,1,768,1,512,1,512,1};
    const int creal[12] = {64,256,300,300,300,256,512,768,256,512,256,512};
    const int cpad[12]  = {64,256,384,384,384,256,512,768,256,512,256,512};
    long gid = (long)blockIdx.x * 256 + threadIdx.x;
    if (gid >= 920192) return;
    const void* srcs[12] = {wexp,bexp,wp1,bp1,wp2,bp2,wconv,bconv,wo1,bo1,wo2,bo2};
    int fl = *flagp;
    int t = 0;
    #pragma unroll
    for (int i = 1; i < 12; ++i) if (gid >= offs[i]) t = i;
    long local = gid - offs[t];
    int r = (int)(local / cpad[t]);
    int c = (int)(local % cpad[t]);
    u16 v = 0;
    if (r < rreal[t] && c < creal[t]) {
        long si = (long)r * creal[t] + c;
        v = fl ? f2bf(((const float*)srcs[t])[si]) : ((const u16*)srcs[t])[si];
    }
    arena[gid] = v;
}

// ---------- input pad/convert: [rows_real x cols_real] -> bf16 [.. x CP] ------
template<int CP>
__global__ void pad2d_kernel(u16* dst, const void* src, int rows_real,
                             int cols_real, long total, const int* flagp)
{
    long gid = (long)blockIdx.x * 256 + threadIdx.x;
    if (gid >= total) return;
    int r = (int)(gid / CP);
    int c = (int)(gid % CP);
    u16 v = 0;
    if (r < rows_real && c < cols_real) {
        long si = (long)r * cols_real + c;
        v = (*flagp) ? f2bf(((const float*)src)[si]) : ((const u16*)src)[si];
    }
    dst[gid] = v;
}

// ---------------- CSR build ----------------
__global__ void count_kernel(const int* dst, int* deg) {
    int e = blockIdx.x * blockDim.x + threadIdx.x;
    if (e < NEDGES) atomicAdd(&deg[dst[e]], 1);
}

__global__ __launch_bounds__(256) void scan1_kernel(const int* deg, int* bsum) {
    __shared__ int s[256];
    int t = threadIdx.x;
    int i = blockIdx.x * 256 + t;
    s[t] = (i < NNODES) ? deg[i] : 0;
    __syncthreads();
    #pragma unroll
    for (int off = 128; off > 0; off >>= 1) {
        if (t < off) s[t] += s[t + off];
        __syncthreads();
    }
    if (t == 0) bsum[blockIdx.x] = s[0];
}

__global__ __launch_bounds__(256) void scan2_kernel(int* bsum, int* row_start) {
    __shared__ int s[256];
    int t = threadIdx.x;
    int v = (t < NSCAN) ? bsum[t] : 0;
    s[t] = v;
    __syncthreads();
    for (int off = 1; off < 256; off <<= 1) {
        int x = (t >= off) ? s[t - off] : 0;
        __syncthreads();
        s[t] += x;
        __syncthreads();
    }
    if (t < NSCAN) bsum[t] = s[t] - v;   // exclusive
    if (t == 0) row_start[NNODES] = NEDGES;
}

__global__ __launch_bounds__(256) void scan3_kernel(const int* deg, const int* bsum,
        int* row_start, int* cursor, float* inv_w) {
    __shared__ int s[256];
    int t = threadIdx.x;
    int i = blockIdx.x * 256 + t;
    int v = (i < NNODES) ? deg[i] : 0;
    s[t] = v;
    __syncthreads();
    for (int off = 1; off < 256; off <<= 1) {
        int x = (t >= off) ? s[t - off] : 0;
        __syncthreads();
        s[t] += x;
        __syncthreads();
    }
    if (i < NNODES) {
        int base = bsum[blockIdx.x] + s[t] - v;
        row_start[i] = base;
        cursor[i] = base;
        inv_w[i] = 1.0f / (float)(v > 0 ? v : 1);
    }
}

__global__ void fill_kernel(const int* src, const int* dst, int* cursor, int* esrc) {
    int e = blockIdx.x * blockDim.x + threadIdx.x;
    if (e < NEDGES) {
        int v = dst[e];
        int pos = atomicAdd(&cursor[v], 1);
        if ((unsigned)pos < (unsigned)NEDGES) esrc[pos] = src[e];
    }
}

// -------- 128x128 MFMA GEMM, BK=64 (2 k-planes per barrier): ------------------
// out = act(A @ W^T + b) (+addsrc). Requires: N mult 128, K mult 64, KA mult 64.
// A rows over-read to bm+127 (must be allocated); garbage rows never stored.
// out must NOT alias A (grid.x>1 blocks share A rows). addsrc==out is safe.
__global__ __launch_bounds__(256) void gemm128_kernel(
    const u16* A, const u16* A2, int KA, int lda,
    const u16* W, int ldw, const u16* bias,
    u16* out, float* outf, int ldo, const u16* addsrc,
    int M, int N, int K, int act)
{
    __shared__ __align__(16) u16 sA[2][128 * 32];   // two 32-deep k-planes, pitch 32
    __shared__ __align__(16) u16 sB[2][128 * 32];
    const int t = threadIdx.x;
    const int wave = t >> 6, lane = t & 63;
    const int quad = lane >> 4, l16 = lane & 15;
    const int wm = wave >> 1, wn = wave & 1;
    const int bm = blockIdx.y * 128, bn = blockIdx.x * 128;
    const int lrow = lane >> 2;          // 0..15
    const int lcol = (lane & 3) * 8;     // 0,8,16,24

    floatx4 acc[4][4];
    #pragma unroll
    for (int i = 0; i < 4; ++i)
        #pragma unroll
        for (int j = 0; j < 4; ++j) acc[i][j] = (floatx4){0.f, 0.f, 0.f, 0.f};

    for (int kt = 0; kt < K; kt += 64) {
        const u16* Ap = A; int kk = kt;
        if (A2 != nullptr && kt >= KA) { Ap = A2; kk = kt - KA; }   // KA mult of 64
        #pragma unroll
        for (int h = 0; h < 2; ++h) {
            #pragma unroll
            for (int c = 0; c < 2; ++c) {
                int r = wave * 32 + c * 16;                  // wave-uniform tile row base
                gload16(Ap + (size_t)(bm + r + lrow) * lda + kk + h * 32 + lcol,
                        &sA[h][r * 32]);
            }
        }
        #pragma unroll
        for (int h = 0; h < 2; ++h) {
            #pragma unroll
            for (int c = 0; c < 2; ++c) {
                int r = wave * 32 + c * 16;
                gload16(W + (size_t)(bn + r + lrow) * ldw + kt + h * 32 + lcol,
                        &sB[h][r * 32]);
            }
        }
        __syncthreads();
        #pragma unroll
        for (int h = 0; h < 2; ++h) {
            short8 af[4], bf[4];
            #pragma unroll
            for (int mt = 0; mt < 4; ++mt)
                af[mt] = *(const short8*)&sA[h][(wm * 64 + mt * 16 + l16) * 32 + quad * 8];
            #pragma unroll
            for (int nt = 0; nt < 4; ++nt)
                bf[nt] = *(const short8*)&sB[h][(wn * 64 + nt * 16 + l16) * 32 + quad * 8];
            #pragma unroll
            for (int mt = 0; mt < 4; ++mt)
                #pragma unroll
                for (int nt = 0; nt < 4; ++nt)
                    acc[mt][nt] = __builtin_amdgcn_mfma_f32_16x16x32_bf16(af[mt], bf[nt], acc[mt][nt], 0, 0, 0);
        }
        __syncthreads();
    }

    // epilogue: C/D col = lane&15, row = quad*4 + reg (HW-verified)
    #pragma unroll
    for (int nt = 0; nt < 4; ++nt) {
        int gn = bn + wn * 64 + nt * 16 + l16;
        float bv = (bias != nullptr) ? bf2f(bias[gn]) : 0.0f;
        #pragma unroll
        for (int mt = 0; mt < 4; ++mt) {
            #pragma unroll
            for (int r = 0; r < 4; ++r) {
                int gm = bm + wm * 64 + mt * 16 + quad * 4 + r;
                if (gm < M) {
                    float v = acc[mt][nt][r] + bv;
                    if (act) v = v > 0.0f ? v : 0.1f * v;
                    if (addsrc != nullptr) v += bf2f(addsrc[(size_t)gm * ldo + gn]);
                    if (outf != nullptr) outf[(size_t)gm * ldo + gn] = v;
                    else out[(size_t)gm * ldo + gn] = f2bf(v);
                }
            }
        }
    }
}

// ------------- neighbor-mean aggregation (pull, CSR, 4 rows in flight) --------
__global__ __launch_bounds__(256) void agg_kernel(
    const u16* h, const int* row_start, const int* esrc,
    const float* inv_w, u16* out)
{
    int gid = blockIdx.x * blockDim.x + threadIdx.x;
    int wid = gid >> 6;
    int lane = gid & 63;
    if (wid >= NNODES) return;
    int e0 = row_start[wid], e1 = row_start[wid + 1];
    e0 = max(0, min(e0, NEDGES));
    e1 = max(e0, min(e1, NEDGES));
    float a0 = 0.f, a1 = 0.f, a2 = 0.f, a3 = 0.f;
    int e = e0;
    for (; e + 4 <= e1; e += 4) {
        // wave-uniform indices (scalar loads); 4 independent 512B row-gathers in flight
        int u0 = esrc[e + 0]; if ((unsigned)u0 >= (unsigned)NNODES) u0 = 0;
        int u1 = esrc[e + 1]; if ((unsigned)u1 >= (unsigned)NNODES) u1 = 0;
        int u2 = esrc[e + 2]; if ((unsigned)u2 >= (unsigned)NNODES) u2 = 0;
        int u3 = esrc[e + 3]; if ((unsigned)u3 >= (unsigned)NNODES) u3 = 0;
        ushort4 t0 = *(const ushort4*)(h + (size_t)u0 * FD + lane * 4);
        ushort4 t1 = *(const ushort4*)(h + (size_t)u1 * FD + lane * 4);
        ushort4 t2 = *(const ushort4*)(h + (size_t)u2 * FD + lane * 4);
        ushort4 t3 = *(const ushort4*)(h + (size_t)u3 * FD + lane * 4);
        a0 += bf2f(t0.x) + bf2f(t1.x) + bf2f(t2.x) + bf2f(t3.x);
        a1 += bf2f(t0.y) + bf2f(t1.y) + bf2f(t2.y) + bf2f(t3.y);
        a2 += bf2f(t0.z) + bf2f(t1.z) + bf2f(t2.z) + bf2f(t3.z);
        a3 += bf2f(t0.w) + bf2f(t1.w) + bf2f(t2.w) + bf2f(t3.w);
    }
    for (; e < e1; ++e) {
        int u = esrc[e];
        if ((unsigned)u >= (unsigned)NNODES) u = 0;
        ushort4 tv = *(const ushort4*)(h + (size_t)u * FD + lane * 4);
        a0 += bf2f(tv.x); a1 += bf2f(tv.y); a2 += bf2f(tv.z); a3 += bf2f(tv.w);
    }
    float s = inv_w[wid];
    ushort4 ov;
    ov.x = f2bf(a0 * s); ov.y = f2bf(a1 * s); ov.z = f2bf(a2 * s); ov.w = f2bf(a3 * s);
    *(ushort4*)(out + (size_t)wid * FD + lane * 4) = ov;
}

// ------------- bf16 row lrelu + L2 normalize (in-place safe) -------------
__global__ __launch_bounds__(256) void norm_kernel(const u16* in, u16* out, int act)
{
    int gid = blockIdx.x * blockDim.x + threadIdx.x;
    int wid = gid >> 6, lane = gid & 63;
    if (wid >= NNODES) return;
    ushort4 tv = *(const ushort4*)(in + (size_t)wid * FD + lane * 4);
    u16 raw[4] = {tv.x, tv.y, tv.z, tv.w};
    float f[4]; float ss = 0.f;
    #pragma unroll
    for (int j = 0; j < 4; ++j) {
        float x = bf2f(raw[j]);
        if (act) x = x > 0.f ? x : 0.1f * x;
        f[j] = x; ss += x * x;
    }
    #pragma unroll
    for (int off = 32; off > 0; off >>= 1) ss += __shfl_xor(ss, off);
    float s = 1.0f / fmaxf(sqrtf(ss), 1e-6f);
    ushort4 ov;
    ov.x = f2bf(f[0] * s); ov.y = f2bf(f[1] * s);
    ov.z = f2bf(f[2] * s); ov.w = f2bf(f[3] * s);
    *(ushort4*)(out + (size_t)wid * FD + lane * 4) = ov;
}

// ------------- f32 final L2 normalize, in place on d_out -------------
__global__ __launch_bounds__(256) void normf_kernel(float* io)
{
    int gid = blockIdx.x * blockDim.x + threadIdx.x;
    int wid = gid >> 6, lane = gid & 63;
    if (wid >= NNODES) return;
    float4 v = *(float4*)(io + (size_t)wid * FD + lane * 4);
    float ss = v.x * v.x + v.y * v.y + v.z * v.z + v.w * v.w;
    #pragma unroll
    for (int off = 32; off > 0; off >>= 1) ss += __shfl_xor(ss, off);
    float s = 1.0f / fmaxf(sqrtf(ss), 1e-6f);
    v.x *= s; v.y *= s; v.z *= s; v.w *= s;
    *(float4*)(io + (size_t)wid * FD + lane * 4) = v;
}

extern "C" void kernel_launch(void* const* d_in, const int* in_sizes, int n_in,
                              void* d_out, int out_size, void* d_ws, size_t ws_size,
                              hipStream_t stream) {
    const void* content = d_in[1];
    const int* src      = (const int*)d_in[2];
    const int* dst      = (const int*)d_in[3];
    const void* emb     = d_in[4];

    // ---- workspace layout (~83.5 MB peak, aliased; all offsets 256B-aligned) --
    char* ws = (char*)d_ws;
    u16* arena = (u16*)(ws);                        // padded weights bf16
    u16* hbuf  = (u16*)(ws + 1840640);              // [50048 x 256] bf16
    u16* buf2  = (u16*)(ws + 27465216);             // [50048 x 256] (h_agg / Wo1-out)
    u16* buf3  = (u16*)(ws + 53089792);             // [50048 x 256] (conv out)
    u16* cpad  = (u16*)(ws + 27465216);             // content_pad [50048 x 384] (init only)
    u16* ebuf  = (u16*)(ws + 65902336);             // emb bf16 [50048 x 64] (init only)
    int*   deg    = (int*)(ws + 78714368);
    int*   rs     = (int*)(ws + 78914560);
    int*   cursor = (int*)(ws + 79114752);
    float* inv_w  = (float*)(ws + 79314944);
    int*   esrc   = (int*)(ws + 79515136);          // 4 MB
    int*   bsum   = (int*)(ws + 83515648);
    int*   flag   = (int*)(ws + 83516672);
    u16* cbuf  = (u16*)d_out;                       // c [50048 x 384] bf16 in d_out (init only)

    u16* aWexp  = arena;            u16* aBexp  = arena + 16384;
    u16* aWp1   = arena + 16640;    u16* aBp1   = arena + 164096;
    u16* aWp2   = arena + 164480;   u16* aBp2   = arena + 262784;
    u16* aWconv = arena + 263040;   u16* aBconv = arena + 656256;
    u16* aWo1   = arena + 657024;   u16* aBo1   = arena + 788096;
    u16* aWo2   = arena + 788608;   u16* aBo2   = arena + 919680;

    const int MB128 = NROWS_PAD / 128;  // 391
    dim3 blk(256);

    // ---- dtype probe + weight conversion/padding ----
    detect_kernel<<<1, 256, 0, stream>>>((const u16*)content, flag);
    convert_kernel<<<(920192 + 255) / 256, 256, 0, stream>>>(arena, flag,
        d_in[5], d_in[6], d_in[7], d_in[8], d_in[9], d_in[10], d_in[11],
        d_in[12], d_in[13], d_in[14], d_in[15], d_in[16]);
    {
        long tot_c = (long)NROWS_PAD * NCPAD;
        pad2d_kernel<NCPAD><<<(int)((tot_c + 255) / 256), 256, 0, stream>>>(
            cpad, content, NNODES, 300, tot_c, flag);
        long tot_e = (long)NROWS_PAD * EDIM;
        pad2d_kernel<EDIM><<<(int)((tot_e + 255) / 256), 256, 0, stream>>>(
            ebuf, emb, NNODES, EDIM, tot_e, flag);
    }

    // ---- init GEMMs (all gemm128, BK=64) ----
    gemm128_kernel<<<dim3(2, MB128), blk, 0, stream>>>(ebuf, nullptr, 0, EDIM,
        aWexp, EDIM, aBexp, hbuf, nullptr, FD, nullptr, NNODES, FD, EDIM, 1);
    gemm128_kernel<<<dim3(3, MB128), blk, 0, stream>>>(cpad, nullptr, 0, NCPAD,
        aWp1, NCPAD, aBp1, cbuf, nullptr, NCPAD, nullptr, NNODES, NCPAD, NCPAD, 1);
    gemm128_kernel<<<dim3(2, MB128), blk, 0, stream>>>(cbuf, nullptr, 0, NCPAD,
        aWp2, NCPAD, aBp2, hbuf, nullptr, FD, hbuf, NNODES, FD, NCPAD, 1);

    // ---- CSR by destination ----
    hipMemsetAsync(deg, 0, (size_t)NNODES * 4, stream);
    count_kernel<<<(NEDGES + 255) / 256, 256, 0, stream>>>(dst, deg);
    scan1_kernel<<<NSCAN, 256, 0, stream>>>(deg, bsum);
    scan2_kernel<<<1, 256, 0, stream>>>(bsum, rs);
    scan3_kernel<<<NSCAN, 256, 0, stream>>>(deg, bsum, rs, cursor, inv_w);
    fill_kernel<<<(NEDGES + 255) / 256, 256, 0, stream>>>(src, dst, cursor, esrc);

    // ---- layers (ping-pong: conv->buf3, Wo1->buf2, Wo2->hbuf) ----
    for (int i = 0; i < 3; ++i) {
        agg_kernel<<<(NNODES * 64) / 256, blk, 0, stream>>>(hbuf, rs, esrc, inv_w, buf2);
        if (i < 2) {
            gemm128_kernel<<<dim3(2, MB128), blk, 0, stream>>>(hbuf, buf2, FD, FD,
                aWconv + (size_t)i * FD * 2 * FD, 2 * FD, aBconv + (size_t)i * FD,
                buf3, nullptr, FD, nullptr, NNODES, FD, 2 * FD, 0);
            norm_kernel<<<(NNODES * 64) / 256, blk, 0, stream>>>(buf3, buf3, 1);
            gemm128_kernel<<<dim3(2, MB128), blk, 0, stream>>>(buf3, nullptr, 0, FD,
                aWo1 + (size_t)i * FD * FD, FD, aBo1 + (size_t)i * FD,
                buf2, nullptr, FD, nullptr, NNODES, FD, FD, 1);
            gemm128_kernel<<<dim3(2, MB128), blk, 0, stream>>>(buf2, nullptr, 0, FD,
                aWo2 + (size_t)i * FD * FD, FD, aBo2 + (size_t)i * FD,
                hbuf, nullptr, FD, nullptr, NNODES, FD, FD, 0);
        } else {
            gemm128_kernel<<<dim3(2, MB128), blk, 0, stream>>>(hbuf, buf2, FD, FD,
                aWconv + (size_t)i * FD * 2 * FD, 2 * FD, aBconv + (size_t)i * FD,
                nullptr, (float*)d_out, FD, nullptr, NNODES, FD, 2 * FD, 0);
            normf_kernel<<<(NNODES * 64) / 256, blk, 0, stream>>>((float*)d_out);
        }
    }
}